// Round 4
// baseline (66.351 us; speedup 1.0000x reference)
//
#include <hip/hip_runtime.h>

// CostVolume (gwc): out[b,g,d,h,w] = (w>=d) ? mean_c( L[b,g*8+c,h,w] * R[b,g*8+c,h,w-d] ) : 0
// B=4, C=320, G=40, Cg=8, D=48, H=64, W=128. Output [4,40,48,64,128] fp32 (252 MB) -> store-BW bound.
//
// R3: true 1KB-contiguous stores PER WAVE INSTRUCTION. Block = (b,g, 4 h-rows); wave = one
// d-tile (8 d); lane = (hp, wt) covers 2 adjacent h rows x 128 w at fixed d -> each
// global_store_dwordx4 writes one contiguous 1KB line. Per d-plane a block writes a 2KB run.
// Nontemporal loads (read-once) + nontemporal stores (zero-reuse). LDS 38.5KB -> 4 blocks/CU.

#define NG 40
#define ND 48
#define NCG 8
#define NH 64
#define NW 128

typedef float f32x4 __attribute__((ext_vector_type(4)));

__global__ __launch_bounds__(384) void cost_volume_kernel(
    const float* __restrict__ left, const float* __restrict__ right,
    float* __restrict__ out)
{
    __shared__ float Ls[4][NCG][NW];      // 16 KB
    __shared__ float Rs[4][NCG][176];     // 22 KB, [0,48) zeros, [48,176) = R row

    const int tid = threadIdx.x;
    const int blk = blockIdx.x;
    const int h4 = blk & 15;              // 16 chunks of 4 h-rows
    const int g  = (blk >> 4) % NG;
    const int b  = blk / (NG * 16);
    const int h0 = h4 << 2;

    // zero the left pads: 4*8*48 floats = 384 float4 (one per thread)
    {
        int rc  = tid / 12;               // 0..31 : (row, c)
        int row = rc >> 3;
        int c   = rc & 7;
        int j   = (tid % 12) * 4;
        *(f32x4*)&Rs[row][c][j] = (f32x4)(0.f);
    }

    // stage L and R: 4 rows x 8 ch x 128 floats = 1024 float4 per input
    // fixed c: 4 rows contiguous (2KB); wave reads 1KB contiguous per instr
    const size_t inbase = (((size_t)b * (NG * NCG) + (size_t)g * NCG) * NH + h0) * NW;
#pragma unroll
    for (int ii = 0; ii < 3; ++ii) {
        int i = tid + ii * 384;
        if (ii < 2 || i < 1024) {
            int c   = i >> 7;             // channel
            int rem = i & 127;            // float4 within 4-row chunk
            int row = rem >> 5;
            int w4  = (rem & 31) << 2;
            const size_t off = inbase + (size_t)c * (NH * NW) + (size_t)rem * 4;
            f32x4 lv = __builtin_nontemporal_load((const f32x4*)&left[off]);
            f32x4 rv = __builtin_nontemporal_load((const f32x4*)&right[off]);
            *(f32x4*)&Ls[row][c][w4]      = lv;
            *(f32x4*)&Rs[row][c][48 + w4] = rv;
        }
    }
    __syncthreads();

    const int wave = tid >> 6;            // 0..5 -> d-tile
    const int lane = tid & 63;
    const int hp   = lane >> 5;           // which row of the pair
    const int wt   = lane & 31;
    const int w0   = wt << 2;
    const int d0   = wave << 3;
    const int xa   = w0 - d0 + 40;        // ≡ 0 (mod 4), in [0,164]

#pragma unroll
    for (int hpair = 0; hpair < 2; ++hpair) {
        const int hl = (hpair << 1) + hp; // local h row 0..3

        float acc[8][4];
#pragma unroll
        for (int d = 0; d < 8; ++d)
#pragma unroll
            for (int w = 0; w < 4; ++w) acc[d][w] = 0.f;

#pragma unroll
        for (int c = 0; c < NCG; ++c) {
            float4 r0 = *(const float4*)&Rs[hl][c][xa];
            float4 r1 = *(const float4*)&Rs[hl][c][xa + 4];
            float4 r2 = *(const float4*)&Rs[hl][c][xa + 8];
            float4 l  = *(const float4*)&Ls[hl][c][w0];
            float rw[12] = {r0.x, r0.y, r0.z, r0.w,
                            r1.x, r1.y, r1.z, r1.w,
                            r2.x, r2.y, r2.z, r2.w};
            float lw[4] = {l.x, l.y, l.z, l.w};
            // out(d0+d, w0+w) needs Rs[hl][c][(w0+w)-(d0+d)+48] -> rw[w-d+8], static in [1,11]
#pragma unroll
            for (int d = 0; d < 8; ++d) {
#pragma unroll
                for (int w = 0; w < 4; ++w) {
                    acc[d][w] = fmaf(lw[w], rw[w - d + 8], acc[d][w]);
                }
            }
        }

        // store: lanes (hp,wt) cover 2 rows x 128 w at fixed d -> 1KB contiguous per instr
        const size_t obase = ((((size_t)b * NG + g) * ND + d0) * NH + (h0 + hl)) * NW + w0;
#pragma unroll
        for (int d = 0; d < 8; ++d) {
            f32x4 o;
            o.x = acc[d][0] * 0.125f;
            o.y = acc[d][1] * 0.125f;
            o.z = acc[d][2] * 0.125f;
            o.w = acc[d][3] * 0.125f;
            __builtin_nontemporal_store(o, (f32x4*)&out[obase + (size_t)d * (NH * NW)]);
        }
    }
}

extern "C" void kernel_launch(void* const* d_in, const int* in_sizes, int n_in,
                              void* d_out, int out_size, void* d_ws, size_t ws_size,
                              hipStream_t stream) {
    const float* left  = (const float*)d_in[0];   // left_gwc  [4,320,64,128]
    const float* right = (const float*)d_in[1];   // right_gwc [4,320,64,128]
    float* out = (float*)d_out;                   // [4,40,48,64,128]
    const int grid = 4 * NG * 16;                 // 2560 blocks (4 h rows each)
    cost_volume_kernel<<<grid, 384, 0, stream>>>(left, right, out);
}

// Round 5
// 63.504 us; speedup vs baseline: 1.0448x; 1.0448x over previous
//
#include <hip/hip_runtime.h>

// CostVolume (gwc): out[b,g,d,h,w] = (w>=d) ? mean_c( L[b,g*8+c,h,w] * R[b,g*8+c,h,w-d] ) : 0
// B=4, C=320, G=40, Cg=8, D=48, H=64, W=128. Output [4,40,48,64,128] fp32 (252 MB) -> store-BW bound.
//
// R4: phase-overlap test. Each block owns (b,g, 8 h-rows) = 4 h-pair slices, grid-stride with
// register-buffered async staging (T14): issue slice s+1's R loads right after writing slice s
// to LDS, so the read stream interleaves with compute+stores continuously. L is NOT staged:
// direct 512B-coalesced global float4 loads, 6x wave reuse served by L1. R single-buffer LDS
// (11 KB) with 48-float zero left-pad (branch-free w>=d mask). nt on read-once R loads and on
// the zero-reuse output stream.

#define NG 40
#define ND 48
#define NCG 8
#define NH 64
#define NW 128

typedef float f32x4 __attribute__((ext_vector_type(4)));

__global__ __launch_bounds__(384) void cost_volume_kernel(
    const float* __restrict__ left, const float* __restrict__ right,
    float* __restrict__ out)
{
    __shared__ float Rs[2][NCG][176];   // 11 KB; [0,48) zeros, [48,176) = R row

    const int tid = threadIdx.x;
    const int blk = blockIdx.x;
    const int oct = blk & 7;            // 8 h-octets of 8 rows
    const int g   = (blk >> 3) % NG;
    const int b   = blk / (NG * 8);
    const int h0  = oct << 3;

    // zero the left pads once: 2*8*48 floats = 192 float4
    if (tid < 192) {
        int hr = tid / 96;
        int r  = tid % 96;
        int c  = r / 12;
        int j  = (r % 12) * 4;
        *(f32x4*)&Rs[hr][c][j] = (f32x4)(0.f);
    }

    // fixed staging assignment: 512 float4 per slice over 384 threads
    const int  i0   = tid;
    const int  c0   = i0 >> 6, rem0 = i0 & 63;
    const int  hr0  = rem0 >> 5, w40 = (rem0 & 31) << 2;
    const int  i1   = tid + 384;                 // only tid<128 (wave-uniform split)
    const int  c1   = i1 >> 6, rem1 = i1 & 63;
    const int  hr1  = rem1 >> 5, w41 = (rem1 & 31) << 2;
    const bool has1 = (tid < 128);

    const size_t base = ((size_t)b * 320 + (size_t)g * NCG) * (size_t)(NH * NW);
    const size_t roff0 = base + (size_t)c0 * (NH * NW) + (size_t)(h0 + hr0) * NW + w40;
    const size_t roff1 = base + (size_t)c1 * (NH * NW) + (size_t)(h0 + hr1) * NW + w41;

    // compute-role constants (same per-slice structure as R2)
    const int hh = tid / 192;          // which h row of the pair
    const int t  = tid % 192;
    const int wt = t & 31;
    const int dt = t / 32;             // 6 d-tiles of 8
    const int w0 = wt << 2;
    const int d0 = dt << 3;
    const int xa = w0 - d0 + 40;       // ≡ 0 (mod 4), in [0,164]

    // prologue: issue slice-0 R loads into registers
    f32x4 v0 = __builtin_nontemporal_load((const f32x4*)&right[roff0]);
    f32x4 v1;
    if (has1) v1 = __builtin_nontemporal_load((const f32x4*)&right[roff1]);

    for (int s = 0; s < 4; ++s) {
        __syncthreads();               // previous slice's readers (or pad init) done
        *(f32x4*)&Rs[hr0][c0][48 + w40] = v0;            // waits vmcnt for v0/v1 here
        if (has1) *(f32x4*)&Rs[hr1][c1][48 + w41] = v1;
        if (s < 3) {                   // issue next slice's loads; latency hides under compute
            const size_t d = (size_t)(2 * (s + 1)) * NW;
            v0 = __builtin_nontemporal_load((const f32x4*)&right[roff0 + d]);
            if (has1) v1 = __builtin_nontemporal_load((const f32x4*)&right[roff1 + d]);
        }
        __syncthreads();

        const int h = h0 + 2 * s + hh;

        float acc[8][4];
#pragma unroll
        for (int d = 0; d < 8; ++d)
#pragma unroll
            for (int w = 0; w < 4; ++w) acc[d][w] = 0.f;

#pragma unroll
        for (int c = 0; c < NCG; ++c) {
            // L direct from global: 512B coalesced per wave, 6x reuse via L1
            float4 l  = *(const float4*)&left[base + (size_t)c * (NH * NW) + (size_t)h * NW + w0];
            float4 r0 = *(const float4*)&Rs[hh][c][xa];
            float4 r1 = *(const float4*)&Rs[hh][c][xa + 4];
            float4 r2 = *(const float4*)&Rs[hh][c][xa + 8];
            float rw[12] = {r0.x, r0.y, r0.z, r0.w,
                            r1.x, r1.y, r1.z, r1.w,
                            r2.x, r2.y, r2.z, r2.w};
            float lw[4] = {l.x, l.y, l.z, l.w};
            // out(d0+d, w0+w) needs Rs[hh][c][(w0+w)-(d0+d)+48] -> rw[w-d+8], static in [1,11]
#pragma unroll
            for (int d = 0; d < 8; ++d) {
#pragma unroll
                for (int w = 0; w < 4; ++w) {
                    acc[d][w] = fmaf(lw[w], rw[w - d + 8], acc[d][w]);
                }
            }
        }

        const size_t obase = ((((size_t)b * NG + g) * ND + d0) * NH + h) * NW + w0;
#pragma unroll
        for (int d = 0; d < 8; ++d) {
            f32x4 o;
            o.x = acc[d][0] * 0.125f;
            o.y = acc[d][1] * 0.125f;
            o.z = acc[d][2] * 0.125f;
            o.w = acc[d][3] * 0.125f;
            __builtin_nontemporal_store(o, (f32x4*)&out[obase + (size_t)d * (NH * NW)]);
        }
    }
}

extern "C" void kernel_launch(void* const* d_in, const int* in_sizes, int n_in,
                              void* d_out, int out_size, void* d_ws, size_t ws_size,
                              hipStream_t stream) {
    const float* left  = (const float*)d_in[0];   // left_gwc  [4,320,64,128]
    const float* right = (const float*)d_in[1];   // right_gwc [4,320,64,128]
    float* out = (float*)d_out;                   // [4,40,48,64,128]
    const int grid = 4 * NG * 8;                  // 1280 blocks (8 h rows each, 4 slices)
    cost_volume_kernel<<<grid, 384, 0, stream>>>(left, right, out);
}